// Round 6
// baseline (812.986 us; speedup 1.0000x reference)
//
#include <hip/hip_runtime.h>
#include <hip/hip_bf16.h>

#define F_IN 128
#define F_HID 64
#define F_OUT 128

// ---------------- zero init (d_ws is poisoned 0xAA before every launch) ----------------
__global__ void zero2_kernel(int* __restrict__ a, int* __restrict__ b, int n) {
    int i = blockIdx.x * blockDim.x + threadIdx.x;
    if (i < n) { a[i] = 0; b[i] = 0; }
}

// ---------------- CSR build ----------------
__global__ void hist_kernel(const int* __restrict__ dst, int* __restrict__ cnt, int E, int Nn) {
    int e = blockIdx.x * blockDim.x + threadIdx.x;
    if (e >= E) return;
    int d = dst[e];
    d = (d < 0) ? 0 : (d >= Nn ? Nn - 1 : d);   // defensive clamp
    atomicAdd(&cnt[d], 1);
}

__global__ void scan1_kernel(const int* __restrict__ cnt, int* __restrict__ off,
                             int* __restrict__ bsum, int n) {
    __shared__ int s[256];
    int tid = threadIdx.x;
    int i = blockIdx.x * 256 + tid;
    int v = (i < n) ? cnt[i] : 0;
    s[tid] = v;
    __syncthreads();
    for (int d = 1; d < 256; d <<= 1) {
        int t = (tid >= d) ? s[tid - d] : 0;
        __syncthreads();
        s[tid] += t;
        __syncthreads();
    }
    if (i < n) off[i] = s[tid] - v;          // block-local exclusive
    if (tid == 255) bsum[blockIdx.x] = s[255];
}

__global__ void scan2_kernel(int* __restrict__ bsum, int nb) {
    __shared__ int s[512];
    int tid = threadIdx.x;
    int v = (tid < nb) ? bsum[tid] : 0;
    s[tid] = v;
    __syncthreads();
    for (int d = 1; d < 512; d <<= 1) {
        int t = (tid >= d) ? s[tid - d] : 0;
        __syncthreads();
        s[tid] += t;
        __syncthreads();
    }
    if (tid < nb) bsum[tid] = s[tid] - v;    // exclusive over block sums
}

__global__ void scan3_kernel(int* __restrict__ off, const int* __restrict__ bsum, int n) {
    int i = blockIdx.x * 256 + threadIdx.x;
    if (i < n) off[i] += bsum[blockIdx.x];
}

__global__ void norm_kernel(const int* __restrict__ cnt, float* __restrict__ norm, int N) {
    int i = blockIdx.x * blockDim.x + threadIdx.x;
    if (i < N) norm[i] = rsqrtf((float)cnt[i] + 1.0f);
}

__global__ void fill_kernel(const int* __restrict__ src, const int* __restrict__ dst,
                            const int* __restrict__ off, int* __restrict__ cur,
                            int* __restrict__ csr_src, int E, int Nn) {
    int e = blockIdx.x * blockDim.x + threadIdx.x;
    if (e >= E) return;
    int d = dst[e];
    d = (d < 0) ? 0 : (d >= Nn ? Nn - 1 : d);
    int s = src[e];
    s = (s < 0) ? 0 : (s >= Nn ? Nn - 1 : s);
    int p = off[d] + atomicAdd(&cur[d], 1);
    p = (p < 0) ? 0 : (p >= E ? E - 1 : p);      // defensive clamp
    csr_src[p] = s;
}

// ---------------- f32 VALU GEMM with fused norm scale ----------------
// C[m][n] = (sum_k A[m][k]*B[k][n]) * norm[m]   (all f32; W staged in LDS)
template<int K, int N>
__global__ void gemm_f32_kernel(const float* __restrict__ A, const float* __restrict__ B,
                                const float* __restrict__ norm,
                                float* __restrict__ C, int M) {
    __shared__ float W[K * N];                    // 32 KB for both shapes
    int tid = threadIdx.x;
    for (int i = tid; i < K * N; i += 256)
        W[i] = B[i];
    __syncthreads();

    constexpr int RPB = 256 / N;                  // rows per block
    int row = blockIdx.x * RPB + tid / N;
    int n   = tid % N;
    if (row >= M) return;

    const float* a = A + (size_t)row * K;
    float acc = 0.0f;
#pragma unroll 8
    for (int k = 0; k < K; k++)
        acc = fmaf(a[k], W[k * N + n], acc);
    C[(size_t)row * N + n] = acc * norm[row];
}

// ---------------- per-node CSR gather + combine (float4-vectorized) ----------------
// h is pre-scaled by norm[src]:  out_i = norm_i*(sum_in h[src] + h_i) + b  [+relu]
// Each thread owns 4 features; F/4 threads per node.
template<int F, bool RELU>
__global__ void gather_kernel(const float* __restrict__ h, const float* __restrict__ norm,
                              const int* __restrict__ off, const int* __restrict__ cnt,
                              const int* __restrict__ csr_src,
                              const float* __restrict__ bias,
                              float* __restrict__ out, int Nn, int E) {
    constexpr int LPN = F / 4;                    // lanes (threads) per node
    int tid   = threadIdx.x;
    int node  = blockIdx.x * (256 / LPN) + tid / LPN;
    int lane4 = tid % LPN;
    if (node >= Nn) return;

    const float4* h4 = (const float4*)h;
    int o0 = off[node];
    int c  = cnt[node];
    if (c < 0) c = 0;
    if (o0 < 0) o0 = 0;
    if (o0 + c > E) c = E - o0;                   // defensive clamp

    float4 sum = make_float4(0.f, 0.f, 0.f, 0.f);
    for (int e = 0; e < c; e++) {
        int s = csr_src[o0 + e];
        s = (s < 0) ? 0 : (s >= Nn ? Nn - 1 : s);
        float4 v = h4[(size_t)s * LPN + lane4];
        sum.x += v.x; sum.y += v.y; sum.z += v.z; sum.w += v.w;
    }
    float4 self = h4[(size_t)node * LPN + lane4];
    float4 b    = ((const float4*)bias)[lane4];
    float nv = norm[node];
    float4 r;
    r.x = nv * (sum.x + self.x) + b.x;
    r.y = nv * (sum.y + self.y) + b.y;
    r.z = nv * (sum.z + self.z) + b.z;
    r.w = nv * (sum.w + self.w) + b.w;
    if (RELU) {
        r.x = fmaxf(r.x, 0.f); r.y = fmaxf(r.y, 0.f);
        r.z = fmaxf(r.z, 0.f); r.w = fmaxf(r.w, 0.f);
    }
    ((float4*)out)[(size_t)node * LPN + lane4] = r;
}

extern "C" void kernel_launch(void* const* d_in, const int* in_sizes, int n_in,
                              void* d_out, int out_size, void* d_ws, size_t ws_size,
                              hipStream_t stream) {
    if (n_in < 6) return;
    const float* x   = (const float*)d_in[0];   // [N,128] f32
    const int*   ei  = (const int*)d_in[1];     // [2,E] int32
    const float* W1  = (const float*)d_in[2];   // [128,64] f32
    const float* b1  = (const float*)d_in[3];   // [64] f32
    const float* W2  = (const float*)d_in[4];   // [64,128] f32
    const float* b2  = (const float*)d_in[5];   // [128] f32
    float*       out = (float*)d_out;           // [N,128] f32 (reference output dtype)

    int Nn = in_sizes[0] / F_IN;
    int E  = in_sizes[1] / 2;
    const int* src = ei;
    const int* dst = ei + E;

    // ---- workspace layout (~59 MB), guarded ----
    size_t o = 0;
    auto alloc = [&](size_t bytes) { size_t cur = o; o += (bytes + 255) & ~(size_t)255; return cur; };
    size_t o_cnt  = alloc((size_t)Nn * 4);
    size_t o_off  = alloc((size_t)(Nn + 1) * 4);
    size_t o_cur  = alloc((size_t)Nn * 4);
    size_t o_bsum = alloc(512 * 4);
    size_t o_nrm  = alloc((size_t)Nn * 4);
    size_t o_csr  = alloc((size_t)E * 4);
    size_t o_h    = alloc((size_t)Nn * F_OUT * 4);   // h2 region; h1 uses its first half
    if (o > ws_size) return;  // signature: absmax ~0.605 (all-zero out) => ws too small
    int nb = (Nn + 255) / 256;
    if (nb > 512) return;

    char* ws = (char*)d_ws;
    int*   cnt  = (int*)(ws + o_cnt);
    int*   off  = (int*)(ws + o_off);
    int*   cur  = (int*)(ws + o_cur);
    int*   bsum = (int*)(ws + o_bsum);
    float* nrm  = (float*)(ws + o_nrm);
    int*   csr  = (int*)(ws + o_csr);
    float* h1   = (float*)(ws + o_h);     // [N,64] f32, first half of region
    float* h2   = (float*)(ws + o_h);     // [N,128] f32, overlays h1 (h1 dead by then)
    // out1 ([N,64] f32, 25.6 MB) lives in the UPPER HALF of d_out (51.2 MB total);
    // it is dead before the final gather overwrites all of d_out.
    float* out1 = out + (size_t)Nn * F_HID;

    // ---- CSR build ----
    zero2_kernel<<<(Nn + 255) / 256, 256, 0, stream>>>(cnt, cur, Nn);
    hist_kernel<<<(E + 255) / 256, 256, 0, stream>>>(dst, cnt, E, Nn);
    scan1_kernel<<<nb, 256, 0, stream>>>(cnt, off, bsum, Nn);
    scan2_kernel<<<1, 512, 0, stream>>>(bsum, nb);
    scan3_kernel<<<nb, 256, 0, stream>>>(off, bsum, Nn);
    norm_kernel<<<(Nn + 255) / 256, 256, 0, stream>>>(cnt, nrm, Nn);
    fill_kernel<<<(E + 255) / 256, 256, 0, stream>>>(src, dst, off, cur, csr, E, Nn);

    // ---- layer 1: h1 = (x@W1)*norm ; gather+relu -> out1 (f32, upper half of d_out) ----
    gemm_f32_kernel<F_IN, F_HID><<<(Nn + 3) / 4, 256, 0, stream>>>(x, W1, nrm, h1, Nn);
    gather_kernel<F_HID, true><<<(Nn + 15) / 16, 256, 0, stream>>>(
        h1, nrm, off, cnt, csr, b1, out1, Nn, E);

    // ---- layer 2: h2 = (out1@W2)*norm ; gather -> d_out (f32) ----
    gemm_f32_kernel<F_HID, F_OUT><<<(Nn + 1) / 2, 256, 0, stream>>>(out1, W2, nrm, h2, Nn);
    gather_kernel<F_OUT, false><<<(Nn + 7) / 8, 256, 0, stream>>>(
        h2, nrm, off, cnt, csr, b2, out, Nn, E);
}

// Round 7
// 505.329 us; speedup vs baseline: 1.6088x; 1.6088x over previous
//
#include <hip/hip_runtime.h>
#include <hip/hip_bf16.h>

#define F_IN 128
#define F_HID 64
#define F_OUT 128

// ---------------- zero init (d_ws is poisoned 0xAA before every launch) ----------------
__global__ void zero2_kernel(int* __restrict__ a, int* __restrict__ b, int n) {
    int i = blockIdx.x * blockDim.x + threadIdx.x;
    if (i < n) { a[i] = 0; b[i] = 0; }
}

// ---------------- CSR build ----------------
__global__ void hist_kernel(const int* __restrict__ dst, int* __restrict__ cnt, int E, int Nn) {
    int e = blockIdx.x * blockDim.x + threadIdx.x;
    if (e >= E) return;
    int d = dst[e];
    d = (d < 0) ? 0 : (d >= Nn ? Nn - 1 : d);
    atomicAdd(&cnt[d], 1);
}

__global__ void scan1_kernel(const int* __restrict__ cnt, int* __restrict__ off,
                             int* __restrict__ bsum, int n) {
    __shared__ int s[256];
    int tid = threadIdx.x;
    int i = blockIdx.x * 256 + tid;
    int v = (i < n) ? cnt[i] : 0;
    s[tid] = v;
    __syncthreads();
    for (int d = 1; d < 256; d <<= 1) {
        int t = (tid >= d) ? s[tid - d] : 0;
        __syncthreads();
        s[tid] += t;
        __syncthreads();
    }
    if (i < n) off[i] = s[tid] - v;
    if (tid == 255) bsum[blockIdx.x] = s[255];
}

__global__ void scan2_kernel(int* __restrict__ bsum, int nb) {
    __shared__ int s[512];
    int tid = threadIdx.x;
    int v = (tid < nb) ? bsum[tid] : 0;
    s[tid] = v;
    __syncthreads();
    for (int d = 1; d < 512; d <<= 1) {
        int t = (tid >= d) ? s[tid - d] : 0;
        __syncthreads();
        s[tid] += t;
        __syncthreads();
    }
    if (tid < nb) bsum[tid] = s[tid] - v;
}

__global__ void scan3_kernel(int* __restrict__ off, const int* __restrict__ bsum, int n) {
    int i = blockIdx.x * 256 + threadIdx.x;
    if (i < n) off[i] += bsum[blockIdx.x];
}

__global__ void norm_kernel(const int* __restrict__ cnt, float* __restrict__ norm, int N) {
    int i = blockIdx.x * blockDim.x + threadIdx.x;
    if (i < N) norm[i] = rsqrtf((float)cnt[i] + 1.0f);
}

__global__ void fill_kernel(const int* __restrict__ src, const int* __restrict__ dst,
                            const int* __restrict__ off, int* __restrict__ cur,
                            int* __restrict__ csr_src, int E, int Nn) {
    int e = blockIdx.x * blockDim.x + threadIdx.x;
    if (e >= E) return;
    int d = dst[e];
    d = (d < 0) ? 0 : (d >= Nn ? Nn - 1 : d);
    int s = src[e];
    s = (s < 0) ? 0 : (s >= Nn ? Nn - 1 : s);
    int p = off[d] + atomicAdd(&cur[d], 1);
    p = (p < 0) ? 0 : (p >= E ? E - 1 : p);
    csr_src[p] = s;
}

// ---------------- register-tiled f32 GEMM ----------------
// C[M][N] = A[M][K] @ B[K][N]  (PRESCALE: ×norm[row])  (BIAS: +bias[col])
// Thread tile 4 rows × 8 cols; W in LDS read as float4; A via global float4.
template<int K, int N, bool PRESCALE, bool BIAS>
__global__ void gemm_tiled(const float* __restrict__ A, const float* __restrict__ B,
                           const float* __restrict__ nrm, const float* __restrict__ bias,
                           float* __restrict__ C, int M) {
    constexpr int CT = N / 8;       // col-threads
    constexpr int RB = (256 / CT) * 4;  // rows per block
    __shared__ float Ws[K * N];     // 32 KB for both shapes

    int tid = threadIdx.x;
    for (int i = tid; i < K * N / 4; i += 256)
        ((float4*)Ws)[i] = ((const float4*)B)[i];
    __syncthreads();

    int ct = tid % CT;
    int rt = tid / CT;
    int row0 = blockIdx.x * RB + rt * 4;
    int c0 = ct * 8;

    float acc[4][8];
#pragma unroll
    for (int r = 0; r < 4; r++)
#pragma unroll
        for (int c = 0; c < 8; c++) acc[r][c] = 0.f;

    for (int kk = 0; kk < K; kk += 4) {
        float4 av[4];
#pragma unroll
        for (int r = 0; r < 4; r++) {
            int row = row0 + r;
            av[r] = (row < M) ? *(const float4*)(A + (size_t)row * K + kk)
                              : make_float4(0.f, 0.f, 0.f, 0.f);
        }
#pragma unroll
        for (int j = 0; j < 4; j++) {
            const float* wrow = Ws + (kk + j) * N + c0;
            float4 w0 = *(const float4*)(wrow);
            float4 w1 = *(const float4*)(wrow + 4);
            float wj[8] = {w0.x, w0.y, w0.z, w0.w, w1.x, w1.y, w1.z, w1.w};
#pragma unroll
            for (int r = 0; r < 4; r++) {
                float a = (j == 0) ? av[r].x : (j == 1) ? av[r].y : (j == 2) ? av[r].z : av[r].w;
#pragma unroll
                for (int c = 0; c < 8; c++)
                    acc[r][c] = fmaf(a, wj[c], acc[r][c]);
            }
        }
    }

    float bcol[8];
    if (BIAS) {
        float4 bb0 = *(const float4*)(bias + c0);
        float4 bb1 = *(const float4*)(bias + c0 + 4);
        bcol[0]=bb0.x; bcol[1]=bb0.y; bcol[2]=bb0.z; bcol[3]=bb0.w;
        bcol[4]=bb1.x; bcol[5]=bb1.y; bcol[6]=bb1.z; bcol[7]=bb1.w;
    }

#pragma unroll
    for (int r = 0; r < 4; r++) {
        int row = row0 + r;
        if (row >= M) continue;
        float scale = PRESCALE ? nrm[row] : 1.0f;
        float4 o0, o1;
        o0.x = acc[r][0]; o0.y = acc[r][1]; o0.z = acc[r][2]; o0.w = acc[r][3];
        o1.x = acc[r][4]; o1.y = acc[r][5]; o1.z = acc[r][6]; o1.w = acc[r][7];
        if (PRESCALE) {
            o0.x*=scale; o0.y*=scale; o0.z*=scale; o0.w*=scale;
            o1.x*=scale; o1.y*=scale; o1.z*=scale; o1.w*=scale;
        }
        if (BIAS) {
            o0.x+=bcol[0]; o0.y+=bcol[1]; o0.z+=bcol[2]; o0.w+=bcol[3];
            o1.x+=bcol[4]; o1.y+=bcol[5]; o1.z+=bcol[6]; o1.w+=bcol[7];
        }
        float* crow = C + (size_t)row * N + c0;
        *(float4*)(crow) = o0;
        *(float4*)(crow + 4) = o1;
    }
}

// ---------------- per-node CSR gather (64 feat, float4) ----------------
// CONV:  out_i = norm_i * relu( norm_i*(sum + self) + bias )   [emits p for next layer]
// !CONV: out_i = norm_i * (sum + self)                          [emits q for gemm2]
template<bool CONV>
__global__ void gather64_kernel(const float* __restrict__ h, const float* __restrict__ norm,
                                const int* __restrict__ off, const int* __restrict__ cnt,
                                const int* __restrict__ csr_src,
                                const float* __restrict__ bias,
                                float* __restrict__ out, int Nn, int E) {
    constexpr int LPN = 16;                       // threads per node (64 feat / 4)
    int tid   = threadIdx.x;
    int node  = blockIdx.x * (256 / LPN) + tid / LPN;
    int lane4 = tid % LPN;
    if (node >= Nn) return;

    const float4* h4 = (const float4*)h;
    int o0 = off[node];
    int c  = cnt[node];
    if (c < 0) c = 0;
    if (o0 < 0) o0 = 0;
    if (o0 + c > E) c = E - o0;

    float4 sum = make_float4(0.f, 0.f, 0.f, 0.f);
    for (int e = 0; e < c; e++) {
        int s = csr_src[o0 + e];
        s = (s < 0) ? 0 : (s >= Nn ? Nn - 1 : s);
        float4 v = h4[(size_t)s * LPN + lane4];
        sum.x += v.x; sum.y += v.y; sum.z += v.z; sum.w += v.w;
    }
    float4 self = h4[(size_t)node * LPN + lane4];
    float nv = norm[node];
    float4 r;
    r.x = nv * (sum.x + self.x);
    r.y = nv * (sum.y + self.y);
    r.z = nv * (sum.z + self.z);
    r.w = nv * (sum.w + self.w);
    if (CONV) {
        float4 b = ((const float4*)bias)[lane4];
        r.x = nv * fmaxf(r.x + b.x, 0.f);
        r.y = nv * fmaxf(r.y + b.y, 0.f);
        r.z = nv * fmaxf(r.z + b.z, 0.f);
        r.w = nv * fmaxf(r.w + b.w, 0.f);
    }
    ((float4*)out)[(size_t)node * LPN + lane4] = r;
}

extern "C" void kernel_launch(void* const* d_in, const int* in_sizes, int n_in,
                              void* d_out, int out_size, void* d_ws, size_t ws_size,
                              hipStream_t stream) {
    if (n_in < 6) return;
    const float* x   = (const float*)d_in[0];   // [N,128] f32
    const int*   ei  = (const int*)d_in[1];     // [2,E] int32
    const float* W1  = (const float*)d_in[2];   // [128,64] f32
    const float* b1  = (const float*)d_in[3];   // [64] f32
    const float* W2  = (const float*)d_in[4];   // [64,128] f32
    const float* b2  = (const float*)d_in[5];   // [128] f32
    float*       out = (float*)d_out;           // [N,128] f32

    int Nn = in_sizes[0] / F_IN;
    int E  = in_sizes[1] / 2;
    const int* src = ei;
    const int* dst = ei + E;

    // ---- workspace layout (~34 MB), guarded ----
    size_t o = 0;
    auto alloc = [&](size_t bytes) { size_t cur = o; o += (bytes + 255) & ~(size_t)255; return cur; };
    size_t o_cnt  = alloc((size_t)Nn * 4);
    size_t o_off  = alloc((size_t)(Nn + 1) * 4);
    size_t o_cur  = alloc((size_t)Nn * 4);
    size_t o_bsum = alloc(512 * 4);
    size_t o_nrm  = alloc((size_t)Nn * 4);
    size_t o_csr  = alloc((size_t)E * 4);
    size_t o_h    = alloc((size_t)Nn * F_HID * 4);   // h1, later overlaid by q
    if (o > ws_size) return;
    int nb = (Nn + 255) / 256;
    if (nb > 512) return;

    char* ws = (char*)d_ws;
    int*   cnt  = (int*)(ws + o_cnt);
    int*   off  = (int*)(ws + o_off);
    int*   cur  = (int*)(ws + o_cur);
    int*   bsum = (int*)(ws + o_bsum);
    float* nrm  = (float*)(ws + o_nrm);
    int*   csr  = (int*)(ws + o_csr);
    float* h1   = (float*)(ws + o_h);     // [N,64] f32
    float* q    = (float*)(ws + o_h);     // [N,64] f32 (overlays h1; h1 dead by then)
    // p ([N,64] f32, 25.6 MB) lives in the UPPER HALF of d_out (51.2 MB);
    // p is dead before gemm2 writes d_out.
    float* p = out + (size_t)Nn * F_HID;

    // ---- CSR build ----
    zero2_kernel<<<(Nn + 255) / 256, 256, 0, stream>>>(cnt, cur, Nn);
    hist_kernel<<<(E + 255) / 256, 256, 0, stream>>>(dst, cnt, E, Nn);
    scan1_kernel<<<nb, 256, 0, stream>>>(cnt, off, bsum, Nn);
    scan2_kernel<<<1, 512, 0, stream>>>(bsum, nb);
    scan3_kernel<<<nb, 256, 0, stream>>>(off, bsum, Nn);
    norm_kernel<<<(Nn + 255) / 256, 256, 0, stream>>>(cnt, nrm, Nn);
    fill_kernel<<<(E + 255) / 256, 256, 0, stream>>>(src, dst, off, cur, csr, E, Nn);

    // ---- layer 1: h1 = (x@W1)*norm ; p = norm*relu(norm*(sum+self)+b1) ----
    {
        constexpr int RB = (256 / (F_HID / 8)) * 4;  // 128 rows/block
        gemm_tiled<F_IN, F_HID, true, false><<<(Nn + RB - 1) / RB, 256, 0, stream>>>(
            x, W1, nrm, nullptr, h1, Nn);
    }
    gather64_kernel<true><<<(Nn + 15) / 16, 256, 0, stream>>>(
        h1, nrm, off, cnt, csr, b1, p, Nn, E);

    // ---- layer 2 (aggregate-then-transform): q = norm*(sum_p+p) ; out = q@W2 + b2 ----
    gather64_kernel<false><<<(Nn + 15) / 16, 256, 0, stream>>>(
        p, nrm, off, cnt, csr, nullptr, q, Nn, E);
    {
        constexpr int RB = (256 / (F_OUT / 8)) * 4;  // 64 rows/block
        gemm_tiled<F_HID, F_OUT, false, true><<<(Nn + RB - 1) / RB, 256, 0, stream>>>(
            q, W2, nullptr, b2, out, Nn);
    }
}

// Round 8
// 389.357 us; speedup vs baseline: 2.0880x; 1.2979x over previous
//
#include <hip/hip_runtime.h>
#include <hip/hip_bf16.h>

#define F_IN 128
#define F_HID 64
#define F_OUT 128
#define BSH 9                 // 512 nodes per bucket
#define BS  (1 << BSH)
#define MAXNB 256

__device__ __forceinline__ int clampi(int v, int lo, int hi) {
    return v < lo ? lo : (v > hi ? hi : v);
}

// ---------------- zero init ----------------
__global__ void zero2_kernel(int* __restrict__ a, int* __restrict__ b, int n) {
    int i = blockIdx.x * blockDim.x + threadIdx.x;
    if (i < n) { a[i] = 0; b[i] = 0; }
}

// ---------------- B1: coarse bucket histogram ----------------
__global__ void bhist_kernel(const int* __restrict__ dst, int* __restrict__ bhist,
                             int E, int Nn, int NB) {
    __shared__ int lh[MAXNB];
    for (int i = threadIdx.x; i < NB; i += 256) lh[i] = 0;
    __syncthreads();
    int chunk = (E + gridDim.x - 1) / gridDim.x;
    int base = blockIdx.x * chunk;
    int end = base + chunk; if (end > E) end = E;
    for (int i = base + threadIdx.x; i < end; i += 256) {
        int d = clampi(dst[i], 0, Nn - 1);
        atomicAdd(&lh[d >> BSH], 1);
    }
    __syncthreads();
    for (int i = threadIdx.x; i < NB; i += 256)
        if (lh[i]) atomicAdd(&bhist[i], lh[i]);
}

// ---------------- exclusive scan over NB buckets (1 block) ----------------
__global__ void bscan_kernel(const int* __restrict__ bhist, int* __restrict__ bbase, int NB) {
    __shared__ int s[MAXNB];
    int t = threadIdx.x;                    // blockDim = 256
    int v = (t < NB) ? bhist[t] : 0;
    s[t] = v;
    __syncthreads();
    for (int d = 1; d < MAXNB; d <<= 1) {
        int x = (t >= d) ? s[t - d] : 0;
        __syncthreads();
        s[t] += x;
        __syncthreads();
    }
    if (t < NB) bbase[t] = s[t] - v;
}

// ---------------- B2: place edges into bucket staging (packed src|dstlo) ----------------
__global__ void bplace_kernel(const int* __restrict__ src, const int* __restrict__ dst,
                              const int* __restrict__ bbase, int* __restrict__ bcur,
                              int* __restrict__ staging, int E, int Nn, int NB) {
    __shared__ int lh[MAXNB];
    __shared__ int gb[MAXNB];
    for (int i = threadIdx.x; i < NB; i += 256) lh[i] = 0;
    __syncthreads();
    int chunk = (E + gridDim.x - 1) / gridDim.x;
    int base = blockIdx.x * chunk;
    int end = base + chunk; if (end > E) end = E;
    for (int i = base + threadIdx.x; i < end; i += 256) {
        int d = clampi(dst[i], 0, Nn - 1);
        atomicAdd(&lh[d >> BSH], 1);
    }
    __syncthreads();
    for (int i = threadIdx.x; i < NB; i += 256) {
        int c = lh[i];
        gb[i] = (c > 0) ? bbase[i] + atomicAdd(&bcur[i], c) : 0;
        lh[i] = 0;                               // reuse as local cursor
    }
    __syncthreads();
    for (int i = base + threadIdx.x; i < end; i += 256) {
        int d = clampi(dst[i], 0, Nn - 1);
        int s = clampi(src[i], 0, Nn - 1);
        int b = d >> BSH;
        int p = gb[b] + atomicAdd(&lh[b], 1);    // contiguous run per block*bucket
        staging[p] = (s << BSH) | (d & (BS - 1));
    }
}

// ---------------- C: per-bucket fine fill -> cnt/off/norm/csr ----------------
__global__ void bfine_kernel(const int* __restrict__ bhist, const int* __restrict__ bbase,
                             const int* __restrict__ staging,
                             int* __restrict__ cnt, int* __restrict__ off,
                             float* __restrict__ nrm, int* __restrict__ csr, int Nn) {
    __shared__ int lcnt[BS];
    __shared__ int loff[BS];
    __shared__ int lcur[BS];
    __shared__ int ps[256];
    int b = blockIdx.x;
    int t = threadIdx.x;
    int base  = bbase[b];
    int count = bhist[b];
    int node0 = b << BSH;

    for (int r = t; r < BS; r += 256) lcnt[r] = 0;
    __syncthreads();
    for (int i = t; i < count; i += 256)
        atomicAdd(&lcnt[staging[base + i] & (BS - 1)], 1);
    __syncthreads();

    // exclusive scan of lcnt[512] with 256 threads (pair + block scan)
    int a0 = lcnt[2 * t], a1 = lcnt[2 * t + 1];
    int pair = a0 + a1;
    ps[t] = pair;
    __syncthreads();
    for (int d = 1; d < 256; d <<= 1) {
        int x = (t >= d) ? ps[t - d] : 0;
        __syncthreads();
        ps[t] += x;
        __syncthreads();
    }
    int excl = ps[t] - pair;
    loff[2 * t]     = excl;
    loff[2 * t + 1] = excl + a0;
    __syncthreads();

    // coalesced global writes of cnt/off/norm
    for (int r = t; r < BS; r += 256) {
        int node = node0 + r;
        if (node < Nn) {
            int c = lcnt[r];
            cnt[node] = c;
            off[node] = base + loff[r];
            nrm[node] = rsqrtf((float)c + 1.0f);
        }
        lcur[r] = 0;
    }
    __syncthreads();

    // place: csr segment [base, base+count) is owned by this block only
    for (int i = t; i < count; i += 256) {
        int v = staging[base + i];
        int r = v & (BS - 1);
        int p = base + loff[r] + atomicAdd(&lcur[r], 1);
        csr[p] = v >> BSH;
    }
}

// ---------------- register-tiled f32 GEMM ----------------
// C[M][N] = A[M][K] @ B[K][N]  (PRESCALE: ×norm[row])  (BIAS: +bias[col])
template<int K, int N, bool PRESCALE, bool BIAS>
__global__ void gemm_tiled(const float* __restrict__ A, const float* __restrict__ B,
                           const float* __restrict__ nrm, const float* __restrict__ bias,
                           float* __restrict__ C, int M) {
    constexpr int CT = N / 8;
    constexpr int RB = (256 / CT) * 4;
    __shared__ float Ws[K * N];

    int tid = threadIdx.x;
    for (int i = tid; i < K * N / 4; i += 256)
        ((float4*)Ws)[i] = ((const float4*)B)[i];
    __syncthreads();

    int ct = tid % CT;
    int rt = tid / CT;
    int row0 = blockIdx.x * RB + rt * 4;
    int c0 = ct * 8;

    float acc[4][8];
#pragma unroll
    for (int r = 0; r < 4; r++)
#pragma unroll
        for (int c = 0; c < 8; c++) acc[r][c] = 0.f;

    for (int kk = 0; kk < K; kk += 4) {
        float4 av[4];
#pragma unroll
        for (int r = 0; r < 4; r++) {
            int row = row0 + r;
            av[r] = (row < M) ? *(const float4*)(A + (size_t)row * K + kk)
                              : make_float4(0.f, 0.f, 0.f, 0.f);
        }
#pragma unroll
        for (int j = 0; j < 4; j++) {
            const float* wrow = Ws + (kk + j) * N + c0;
            float4 w0 = *(const float4*)(wrow);
            float4 w1 = *(const float4*)(wrow + 4);
            float wj[8] = {w0.x, w0.y, w0.z, w0.w, w1.x, w1.y, w1.z, w1.w};
#pragma unroll
            for (int r = 0; r < 4; r++) {
                float a = (j == 0) ? av[r].x : (j == 1) ? av[r].y : (j == 2) ? av[r].z : av[r].w;
#pragma unroll
                for (int c = 0; c < 8; c++)
                    acc[r][c] = fmaf(a, wj[c], acc[r][c]);
            }
        }
    }

    float bcol[8];
    if (BIAS) {
        float4 bb0 = *(const float4*)(bias + c0);
        float4 bb1 = *(const float4*)(bias + c0 + 4);
        bcol[0]=bb0.x; bcol[1]=bb0.y; bcol[2]=bb0.z; bcol[3]=bb0.w;
        bcol[4]=bb1.x; bcol[5]=bb1.y; bcol[6]=bb1.z; bcol[7]=bb1.w;
    }

#pragma unroll
    for (int r = 0; r < 4; r++) {
        int row = row0 + r;
        if (row >= M) continue;
        float scale = PRESCALE ? nrm[row] : 1.0f;
        float4 o0, o1;
        o0.x = acc[r][0]; o0.y = acc[r][1]; o0.z = acc[r][2]; o0.w = acc[r][3];
        o1.x = acc[r][4]; o1.y = acc[r][5]; o1.z = acc[r][6]; o1.w = acc[r][7];
        if (PRESCALE) {
            o0.x*=scale; o0.y*=scale; o0.z*=scale; o0.w*=scale;
            o1.x*=scale; o1.y*=scale; o1.z*=scale; o1.w*=scale;
        }
        if (BIAS) {
            o0.x+=bcol[0]; o0.y+=bcol[1]; o0.z+=bcol[2]; o0.w+=bcol[3];
            o1.x+=bcol[4]; o1.y+=bcol[5]; o1.z+=bcol[6]; o1.w+=bcol[7];
        }
        float* crow = C + (size_t)row * N + c0;
        *(float4*)(crow) = o0;
        *(float4*)(crow + 4) = o1;
    }
}

// ---------------- per-node CSR gather (64 feat, float4) ----------------
// CONV:  out_i = norm_i * relu( norm_i*(sum + self) + bias )   [emits p]
// !CONV: out_i = norm_i * (sum + self)                          [emits q]
template<bool CONV>
__global__ void gather64_kernel(const float* __restrict__ h, const float* __restrict__ norm,
                                const int* __restrict__ off, const int* __restrict__ cnt,
                                const int* __restrict__ csr_src,
                                const float* __restrict__ bias,
                                float* __restrict__ out, int Nn, int E) {
    constexpr int LPN = 16;
    int tid   = threadIdx.x;
    int node  = blockIdx.x * (256 / LPN) + tid / LPN;
    int lane4 = tid % LPN;
    if (node >= Nn) return;

    const float4* h4 = (const float4*)h;
    int o0 = off[node];
    int c  = cnt[node];
    if (c < 0) c = 0;
    if (o0 < 0) o0 = 0;
    if (o0 + c > E) c = E - o0;

    float4 sum = make_float4(0.f, 0.f, 0.f, 0.f);
    for (int e = 0; e < c; e++) {
        int s = csr_src[o0 + e];
        s = clampi(s, 0, Nn - 1);
        float4 v = h4[(size_t)s * LPN + lane4];
        sum.x += v.x; sum.y += v.y; sum.z += v.z; sum.w += v.w;
    }
    float4 self = h4[(size_t)node * LPN + lane4];
    float nv = norm[node];
    float4 r;
    r.x = nv * (sum.x + self.x);
    r.y = nv * (sum.y + self.y);
    r.z = nv * (sum.z + self.z);
    r.w = nv * (sum.w + self.w);
    if (CONV) {
        float4 b = ((const float4*)bias)[lane4];
        r.x = nv * fmaxf(r.x + b.x, 0.f);
        r.y = nv * fmaxf(r.y + b.y, 0.f);
        r.z = nv * fmaxf(r.z + b.z, 0.f);
        r.w = nv * fmaxf(r.w + b.w, 0.f);
    }
    ((float4*)out)[(size_t)node * LPN + lane4] = r;
}

extern "C" void kernel_launch(void* const* d_in, const int* in_sizes, int n_in,
                              void* d_out, int out_size, void* d_ws, size_t ws_size,
                              hipStream_t stream) {
    if (n_in < 6) return;
    const float* x   = (const float*)d_in[0];   // [N,128] f32
    const int*   ei  = (const int*)d_in[1];     // [2,E] int32
    const float* W1  = (const float*)d_in[2];   // [128,64] f32
    const float* b1  = (const float*)d_in[3];   // [64] f32
    const float* W2  = (const float*)d_in[4];   // [64,128] f32
    const float* b2  = (const float*)d_in[5];   // [128] f32
    float*       out = (float*)d_out;           // [N,128] f32

    int Nn = in_sizes[0] / F_IN;
    int E  = in_sizes[1] / 2;
    const int* src = ei;
    const int* dst = ei + E;

    int NB = (Nn + BS - 1) >> BSH;              // 196 for 100k
    if (NB > MAXNB) return;
    // src must fit in 32-BSH bits for staging pack
    if (Nn > (1 << (31 - BSH))) return;

    // ---- workspace layout (~40 MB), guarded ----
    size_t o = 0;
    auto alloc = [&](size_t bytes) { size_t cur = o; o += (bytes + 255) & ~(size_t)255; return cur; };
    size_t o_cnt   = alloc((size_t)Nn * 4);
    size_t o_off   = alloc((size_t)Nn * 4);
    size_t o_nrm   = alloc((size_t)Nn * 4);
    size_t o_csr   = alloc((size_t)E * 4);
    size_t o_stg   = alloc((size_t)E * 4);
    size_t o_bh    = alloc(MAXNB * 4);
    size_t o_bb    = alloc(MAXNB * 4);
    size_t o_bc    = alloc(MAXNB * 4);
    size_t o_h     = alloc((size_t)Nn * F_HID * 4);
    if (o > ws_size) return;

    char* ws = (char*)d_ws;
    int*   cnt   = (int*)(ws + o_cnt);
    int*   off   = (int*)(ws + o_off);
    float* nrm   = (float*)(ws + o_nrm);
    int*   csr   = (int*)(ws + o_csr);
    int*   stg   = (int*)(ws + o_stg);
    int*   bh    = (int*)(ws + o_bh);
    int*   bb    = (int*)(ws + o_bb);
    int*   bc    = (int*)(ws + o_bc);
    float* h1    = (float*)(ws + o_h);
    float* q     = (float*)(ws + o_h);          // overlays h1 (dead by then)
    float* p     = out + (size_t)Nn * F_HID;    // upper half of d_out, dead before gemm2

    // ---- CSR build (bucketed, write-local) ----
    zero2_kernel<<<1, 256, 0, stream>>>(bh, bc, MAXNB);
    bhist_kernel<<<256, 256, 0, stream>>>(dst, bh, E, Nn, NB);
    bscan_kernel<<<1, 256, 0, stream>>>(bh, bb, NB);
    bplace_kernel<<<256, 256, 0, stream>>>(src, dst, bb, bc, stg, E, Nn, NB);
    bfine_kernel<<<NB, 256, 0, stream>>>(bh, bb, stg, cnt, off, nrm, csr, Nn);

    // ---- layer 1: h1 = (x@W1)*norm ; p = norm*relu(norm*(sum+self)+b1) ----
    {
        constexpr int RB = (256 / (F_HID / 8)) * 4;  // 128 rows/block
        gemm_tiled<F_IN, F_HID, true, false><<<(Nn + RB - 1) / RB, 256, 0, stream>>>(
            x, W1, nrm, nullptr, h1, Nn);
    }
    gather64_kernel<true><<<(Nn + 15) / 16, 256, 0, stream>>>(
        h1, nrm, off, cnt, csr, b1, p, Nn, E);

    // ---- layer 2: q = norm*(sum_p+p) ; out = q@W2 + b2 ----
    gather64_kernel<false><<<(Nn + 15) / 16, 256, 0, stream>>>(
        p, nrm, off, cnt, csr, nullptr, q, Nn, E);
    {
        constexpr int RB = (256 / (F_OUT / 8)) * 4;  // 64 rows/block
        gemm_tiled<F_HID, F_OUT, false, true><<<(Nn + RB - 1) / RB, 256, 0, stream>>>(
            q, W2, nullptr, b2, out, Nn);
    }
}

// Round 9
// 371.501 us; speedup vs baseline: 2.1884x; 1.0481x over previous
//
#include <hip/hip_runtime.h>
#include <hip/hip_bf16.h>

#define F_IN 128
#define F_HID 64
#define F_OUT 128
#define BSH 9                 // 512 nodes per bucket
#define BS  (1 << BSH)
#define MAXNB 256

__device__ __forceinline__ int clampi(int v, int lo, int hi) {
    return v < lo ? lo : (v > hi ? hi : v);
}

// ---------------- zero init ----------------
__global__ void zero2_kernel(int* __restrict__ a, int* __restrict__ b, int n) {
    int i = blockIdx.x * blockDim.x + threadIdx.x;
    if (i < n) { a[i] = 0; b[i] = 0; }
}

// ---------------- B1: coarse bucket histogram ----------------
__global__ void bhist_kernel(const int* __restrict__ dst, int* __restrict__ bhist,
                             int E, int Nn, int NB) {
    __shared__ int lh[MAXNB];
    for (int i = threadIdx.x; i < NB; i += 256) lh[i] = 0;
    __syncthreads();
    int chunk = (E + gridDim.x - 1) / gridDim.x;
    int base = blockIdx.x * chunk;
    int end = base + chunk; if (end > E) end = E;
    for (int i = base + threadIdx.x; i < end; i += 256) {
        int d = clampi(dst[i], 0, Nn - 1);
        atomicAdd(&lh[d >> BSH], 1);
    }
    __syncthreads();
    for (int i = threadIdx.x; i < NB; i += 256)
        if (lh[i]) atomicAdd(&bhist[i], lh[i]);
}

// ---------------- exclusive scan over NB buckets (1 block) ----------------
__global__ void bscan_kernel(const int* __restrict__ bhist, int* __restrict__ bbase, int NB) {
    __shared__ int s[MAXNB];
    int t = threadIdx.x;                    // blockDim = 256
    int v = (t < NB) ? bhist[t] : 0;
    s[t] = v;
    __syncthreads();
    for (int d = 1; d < MAXNB; d <<= 1) {
        int x = (t >= d) ? s[t - d] : 0;
        __syncthreads();
        s[t] += x;
        __syncthreads();
    }
    if (t < NB) bbase[t] = s[t] - v;
}

// ---------------- B2: place edges into bucket staging (packed src|dstlo) ----------------
__global__ void bplace_kernel(const int* __restrict__ src, const int* __restrict__ dst,
                              const int* __restrict__ bbase, int* __restrict__ bcur,
                              int* __restrict__ staging, int E, int Nn, int NB) {
    __shared__ int lh[MAXNB];
    __shared__ int gb[MAXNB];
    for (int i = threadIdx.x; i < NB; i += 256) lh[i] = 0;
    __syncthreads();
    int chunk = (E + gridDim.x - 1) / gridDim.x;
    int base = blockIdx.x * chunk;
    int end = base + chunk; if (end > E) end = E;
    for (int i = base + threadIdx.x; i < end; i += 256) {
        int d = clampi(dst[i], 0, Nn - 1);
        atomicAdd(&lh[d >> BSH], 1);
    }
    __syncthreads();
    for (int i = threadIdx.x; i < NB; i += 256) {
        int c = lh[i];
        gb[i] = (c > 0) ? bbase[i] + atomicAdd(&bcur[i], c) : 0;
        lh[i] = 0;                               // reuse as local cursor
    }
    __syncthreads();
    for (int i = base + threadIdx.x; i < end; i += 256) {
        int d = clampi(dst[i], 0, Nn - 1);
        int s = clampi(src[i], 0, Nn - 1);
        int b = d >> BSH;
        int p = gb[b] + atomicAdd(&lh[b], 1);    // contiguous run per block*bucket
        staging[p] = (s << BSH) | (d & (BS - 1));
    }
}

// ---------------- C: per-bucket fine fill -> cnt/off/norm/csr ----------------
__global__ void bfine_kernel(const int* __restrict__ bhist, const int* __restrict__ bbase,
                             const int* __restrict__ staging,
                             int* __restrict__ cnt, int* __restrict__ off,
                             float* __restrict__ nrm, int* __restrict__ csr, int Nn) {
    __shared__ int lcnt[BS];
    __shared__ int loff[BS];
    __shared__ int lcur[BS];
    __shared__ int ps[256];
    int b = blockIdx.x;
    int t = threadIdx.x;
    int base  = bbase[b];
    int count = bhist[b];
    int node0 = b << BSH;

    for (int r = t; r < BS; r += 256) lcnt[r] = 0;
    __syncthreads();
    for (int i = t; i < count; i += 256)
        atomicAdd(&lcnt[staging[base + i] & (BS - 1)], 1);
    __syncthreads();

    // exclusive scan of lcnt[512] with 256 threads
    int a0 = lcnt[2 * t], a1 = lcnt[2 * t + 1];
    int pair = a0 + a1;
    ps[t] = pair;
    __syncthreads();
    for (int d = 1; d < 256; d <<= 1) {
        int x = (t >= d) ? ps[t - d] : 0;
        __syncthreads();
        ps[t] += x;
        __syncthreads();
    }
    int excl = ps[t] - pair;
    loff[2 * t]     = excl;
    loff[2 * t + 1] = excl + a0;
    __syncthreads();

    for (int r = t; r < BS; r += 256) {
        int node = node0 + r;
        if (node < Nn) {
            int c = lcnt[r];
            cnt[node] = c;
            off[node] = base + loff[r];
            nrm[node] = rsqrtf((float)c + 1.0f);
        }
        lcur[r] = 0;
    }
    __syncthreads();

    for (int i = t; i < count; i += 256) {
        int v = staging[base + i];
        int r = v & (BS - 1);
        int p = base + loff[r] + atomicAdd(&lcur[r], 1);
        csr[p] = v >> BSH;
    }
}

// ---------------- register-tiled f32 GEMM ----------------
template<int K, int N, bool PRESCALE, bool BIAS>
__global__ void gemm_tiled(const float* __restrict__ A, const float* __restrict__ B,
                           const float* __restrict__ nrm, const float* __restrict__ bias,
                           float* __restrict__ C, int M) {
    constexpr int CT = N / 8;
    constexpr int RB = (256 / CT) * 4;
    __shared__ float Ws[K * N];

    int tid = threadIdx.x;
    for (int i = tid; i < K * N / 4; i += 256)
        ((float4*)Ws)[i] = ((const float4*)B)[i];
    __syncthreads();

    int ct = tid % CT;
    int rt = tid / CT;
    int row0 = blockIdx.x * RB + rt * 4;
    int c0 = ct * 8;

    float acc[4][8];
#pragma unroll
    for (int r = 0; r < 4; r++)
#pragma unroll
        for (int c = 0; c < 8; c++) acc[r][c] = 0.f;

    for (int kk = 0; kk < K; kk += 4) {
        float4 av[4];
#pragma unroll
        for (int r = 0; r < 4; r++) {
            int row = row0 + r;
            av[r] = (row < M) ? *(const float4*)(A + (size_t)row * K + kk)
                              : make_float4(0.f, 0.f, 0.f, 0.f);
        }
#pragma unroll
        for (int j = 0; j < 4; j++) {
            const float* wrow = Ws + (kk + j) * N + c0;
            float4 w0 = *(const float4*)(wrow);
            float4 w1 = *(const float4*)(wrow + 4);
            float wj[8] = {w0.x, w0.y, w0.z, w0.w, w1.x, w1.y, w1.z, w1.w};
#pragma unroll
            for (int r = 0; r < 4; r++) {
                float a = (j == 0) ? av[r].x : (j == 1) ? av[r].y : (j == 2) ? av[r].z : av[r].w;
#pragma unroll
                for (int c = 0; c < 8; c++)
                    acc[r][c] = fmaf(a, wj[c], acc[r][c]);
            }
        }
    }

    float bcol[8];
    if (BIAS) {
        float4 bb0 = *(const float4*)(bias + c0);
        float4 bb1 = *(const float4*)(bias + c0 + 4);
        bcol[0]=bb0.x; bcol[1]=bb0.y; bcol[2]=bb0.z; bcol[3]=bb0.w;
        bcol[4]=bb1.x; bcol[5]=bb1.y; bcol[6]=bb1.z; bcol[7]=bb1.w;
    }

#pragma unroll
    for (int r = 0; r < 4; r++) {
        int row = row0 + r;
        if (row >= M) continue;
        float scale = PRESCALE ? nrm[row] : 1.0f;
        float4 o0, o1;
        o0.x = acc[r][0]; o0.y = acc[r][1]; o0.z = acc[r][2]; o0.w = acc[r][3];
        o1.x = acc[r][4]; o1.y = acc[r][5]; o1.z = acc[r][6]; o1.w = acc[r][7];
        if (PRESCALE) {
            o0.x*=scale; o0.y*=scale; o0.z*=scale; o0.w*=scale;
            o1.x*=scale; o1.y*=scale; o1.z*=scale; o1.w*=scale;
        }
        if (BIAS) {
            o0.x+=bcol[0]; o0.y+=bcol[1]; o0.z+=bcol[2]; o0.w+=bcol[3];
            o1.x+=bcol[4]; o1.y+=bcol[5]; o1.z+=bcol[6]; o1.w+=bcol[7];
        }
        float* crow = C + (size_t)row * N + c0;
        *(float4*)(crow) = o0;
        *(float4*)(crow + 4) = o1;
    }
}

// ---------------- per-node CSR gather: ONE WAVE PER NODE (64 lanes = 64 feats) ----------------
// CONV:  out_i = norm_i * relu( norm_i*(sum + self) + bias )   [emits p]
// !CONV: out_i = norm_i * (sum + self)                          [emits q]
// node is wave-uniform (readfirstlane) -> off/cnt/csr go through the scalar path;
// edge loop unrolled x4 -> 4 outstanding random h-row loads per wave.
template<bool CONV>
__global__ void gather64_kernel(const float* __restrict__ h, const float* __restrict__ norm,
                                const int* __restrict__ off, const int* __restrict__ cnt,
                                const int* __restrict__ csr_src,
                                const float* __restrict__ bias,
                                float* __restrict__ out, int Nn, int E) {
    int wave = (blockIdx.x * blockDim.x + threadIdx.x) >> 6;
    int lane = threadIdx.x & 63;
    int node = __builtin_amdgcn_readfirstlane(wave);
    if (node >= Nn) return;

    int o0 = __builtin_amdgcn_readfirstlane(off[node]);
    int c  = __builtin_amdgcn_readfirstlane(cnt[node]);
    if (c < 0) c = 0;
    if (o0 < 0) o0 = 0;
    if (o0 + c > E) c = E - o0;

    const int* ce = csr_src + o0;
    float sum = 0.0f;
    int e = 0;
    for (; e + 4 <= c; e += 4) {
        int s0 = clampi(ce[e],     0, Nn - 1);
        int s1 = clampi(ce[e + 1], 0, Nn - 1);
        int s2 = clampi(ce[e + 2], 0, Nn - 1);
        int s3 = clampi(ce[e + 3], 0, Nn - 1);
        float v0 = h[(size_t)s0 * 64 + lane];
        float v1 = h[(size_t)s1 * 64 + lane];
        float v2 = h[(size_t)s2 * 64 + lane];
        float v3 = h[(size_t)s3 * 64 + lane];
        sum += v0; sum += v1; sum += v2; sum += v3;
    }
    for (; e < c; e++) {
        int s = clampi(ce[e], 0, Nn - 1);
        sum += h[(size_t)s * 64 + lane];
    }
    float self = h[(size_t)node * 64 + lane];
    float nv = norm[node];
    float r = nv * (sum + self);
    if (CONV) r = nv * fmaxf(r + bias[lane], 0.0f);
    out[(size_t)node * 64 + lane] = r;
}

extern "C" void kernel_launch(void* const* d_in, const int* in_sizes, int n_in,
                              void* d_out, int out_size, void* d_ws, size_t ws_size,
                              hipStream_t stream) {
    if (n_in < 6) return;
    const float* x   = (const float*)d_in[0];   // [N,128] f32
    const int*   ei  = (const int*)d_in[1];     // [2,E] int32
    const float* W1  = (const float*)d_in[2];   // [128,64] f32
    const float* b1  = (const float*)d_in[3];   // [64] f32
    const float* W2  = (const float*)d_in[4];   // [64,128] f32
    const float* b2  = (const float*)d_in[5];   // [128] f32
    float*       out = (float*)d_out;           // [N,128] f32

    int Nn = in_sizes[0] / F_IN;
    int E  = in_sizes[1] / 2;
    const int* src = ei;
    const int* dst = ei + E;

    int NB = (Nn + BS - 1) >> BSH;              // 196 for 100k
    if (NB > MAXNB) return;
    if (Nn > (1 << (31 - BSH))) return;

    // ---- workspace layout (~40 MB), guarded ----
    size_t o = 0;
    auto alloc = [&](size_t bytes) { size_t cur = o; o += (bytes + 255) & ~(size_t)255; return cur; };
    size_t o_cnt   = alloc((size_t)Nn * 4);
    size_t o_off   = alloc((size_t)Nn * 4);
    size_t o_nrm   = alloc((size_t)Nn * 4);
    size_t o_csr   = alloc((size_t)E * 4);
    size_t o_stg   = alloc((size_t)E * 4);
    size_t o_bh    = alloc(MAXNB * 4);
    size_t o_bb    = alloc(MAXNB * 4);
    size_t o_bc    = alloc(MAXNB * 4);
    size_t o_h     = alloc((size_t)Nn * F_HID * 4);
    if (o > ws_size) return;

    char* ws = (char*)d_ws;
    int*   cnt   = (int*)(ws + o_cnt);
    int*   off   = (int*)(ws + o_off);
    float* nrm   = (float*)(ws + o_nrm);
    int*   csr   = (int*)(ws + o_csr);
    int*   stg   = (int*)(ws + o_stg);
    int*   bh    = (int*)(ws + o_bh);
    int*   bb    = (int*)(ws + o_bb);
    int*   bc    = (int*)(ws + o_bc);
    float* h1    = (float*)(ws + o_h);
    float* q     = (float*)(ws + o_h);          // overlays h1 (dead by then)
    float* p     = out + (size_t)Nn * F_HID;    // upper half of d_out, dead before gemm2

    // ---- CSR build (bucketed, write-local) ----
    zero2_kernel<<<1, 256, 0, stream>>>(bh, bc, MAXNB);
    bhist_kernel<<<256, 256, 0, stream>>>(dst, bh, E, Nn, NB);
    bscan_kernel<<<1, 256, 0, stream>>>(bh, bb, NB);
    bplace_kernel<<<256, 256, 0, stream>>>(src, dst, bb, bc, stg, E, Nn, NB);
    bfine_kernel<<<NB, 256, 0, stream>>>(bh, bb, stg, cnt, off, nrm, csr, Nn);

    // ---- layer 1: h1 = (x@W1)*norm ; p = norm*relu(norm*(sum+self)+b1) ----
    {
        constexpr int RB = (256 / (F_HID / 8)) * 4;  // 128 rows/block
        gemm_tiled<F_IN, F_HID, true, false><<<(Nn + RB - 1) / RB, 256, 0, stream>>>(
            x, W1, nrm, nullptr, h1, Nn);
    }
    gather64_kernel<true><<<(Nn + 3) / 4, 256, 0, stream>>>(
        h1, nrm, off, cnt, csr, b1, p, Nn, E);

    // ---- layer 2: q = norm*(sum_p+p) ; out = q@W2 + b2 ----
    gather64_kernel<false><<<(Nn + 3) / 4, 256, 0, stream>>>(
        p, nrm, off, cnt, csr, nullptr, q, Nn, E);
    {
        constexpr int RB = (256 / (F_OUT / 8)) * 4;  // 64 rows/block
        gemm_tiled<F_HID, F_OUT, false, true><<<(Nn + RB - 1) / RB, 256, 0, stream>>>(
            q, W2, nullptr, b2, out, Nn);
    }
}